// Round 6
// baseline (178.881 us; speedup 1.0000x reference)
//
#include <hip/hip_runtime.h>
#include <cmath>

#define Tn  2048
#define Cn  1024
#define Hn  64
#define BTn 16384

typedef _Float16 f16x8 __attribute__((ext_vector_type(8)));
typedef _Float16 f16x4 __attribute__((ext_vector_type(4)));
typedef _Float16 f16x2 __attribute__((ext_vector_type(2)));
typedef float    f32x4 __attribute__((ext_vector_type(4)));

// ---------------------------------------------------------------------------
// prep: transpose Wq|Wk|Wv (each [Cn][64] fp32) into Wt[192][Cn] f16
// ---------------------------------------------------------------------------
__global__ __launch_bounds__(256) void prep_w_kernel(
    const float* __restrict__ Wq, const float* __restrict__ Wk,
    const float* __restrict__ Wv, _Float16* __restrict__ Wt)
{
    __shared__ float ts[64][65];
    const int blk = blockIdx.x;          // 48 = 3 proj * 16 c-tiles
    const int p   = blk >> 4;
    const int c0  = (blk & 15) * 64;
    const float* __restrict__ W = (p == 0) ? Wq : (p == 1) ? Wk : Wv;
    const int tid = threadIdx.x;
    #pragma unroll
    for (int it = 0; it < 16; it++) {
        int idx = tid + it * 256;
        int c = idx >> 6, n = idx & 63;
        ts[c][n] = W[(size_t)(c0 + c) * Hn + n];
    }
    __syncthreads();
    #pragma unroll
    for (int it = 0; it < 16; it++) {
        int idx = tid + it * 256;
        int n = idx >> 6, c = idx & 63;
        Wt[(size_t)(p * 64 + n) * Cn + c0 + c] = (_Float16)ts[c][n];
    }
}

// ---------------------------------------------------------------------------
// proj: barrier-free K-loop, 512 thr = 8 waves (2m x 4n). Block = 32 rows x
// all 192 out-cols. Wave (wr,wc): m-tile wr*16, n-range wc*48 (3 n-tiles,
// 3 MFMA/iter). x-tile staged to LDS once (f16, stride 1032: conflict-free);
// W B-frags direct from global (Wt 384 KB, L2-resident). 16 waves/CU.
// Epilogue: RoPE on q/k (q pre-scaled H^-1/2); v stored TRANSPOSED vT[b][h][t].
// ---------------------------------------------------------------------------
#define XSP 1032

__global__ __launch_bounds__(512) void proj_kernel(
    const float* __restrict__ x, const _Float16* __restrict__ Wt,
    _Float16* __restrict__ qh, _Float16* __restrict__ kh, _Float16* __restrict__ vT)
{
    __shared__ _Float16 xs[32 * XSP];    // 66 KB -> 2 blocks/CU
    const int row0 = blockIdx.x * 32;
    const int tid  = threadIdx.x;
    const int wave = tid >> 6, lane = tid & 63;
    const int quad = lane >> 4, l15 = lane & 15;
    const int wr = wave >> 2, wc = wave & 3;

    // Stage x (32 rows x 1024 fp32 -> f16) once. Coalesced float4 reads.
    #pragma unroll 8
    for (int it = 0; it < 16; it++) {
        int idx = tid + it * 512;        // 8192 float4
        int r = idx >> 8, c4 = idx & 255;
        float4 xv = *(const float4*)&x[(size_t)(row0 + r) * Cn + c4 * 4];
        f16x4 hv = { (_Float16)xv.x, (_Float16)xv.y, (_Float16)xv.z, (_Float16)xv.w };
        *(f16x4*)&xs[r * XSP + c4 * 4] = hv;
    }
    __syncthreads();                     // the only barrier

    f32x4 acc[3] = {};
    const _Float16* __restrict__ wb = Wt + (size_t)(wc * 48 + l15) * Cn + quad * 8;

    #pragma unroll 4
    for (int kc = 0; kc < Cn; kc += 32) {
        f16x8 b0 = *(const f16x8*)&wb[kc];
        f16x8 b1 = *(const f16x8*)&wb[16 * Cn + kc];
        f16x8 b2 = *(const f16x8*)&wb[32 * Cn + kc];
        f16x8 a  = *(const f16x8*)&xs[(wr * 16 + l15) * XSP + kc + quad * 8];
        acc[0] = __builtin_amdgcn_mfma_f32_16x16x32_f16(a, b0, acc[0], 0, 0, 0);
        acc[1] = __builtin_amdgcn_mfma_f32_16x16x32_f16(a, b1, acc[1], 0, 0, 0);
        acc[2] = __builtin_amdgcn_mfma_f32_16x16x32_f16(a, b2, acc[2], 0, 0, 0);
    }

    // Epilogue
    const int bidx = row0 >> 11;
    #pragma unroll
    for (int nt = 0; nt < 3; nt++) {
        const int n = wc * 48 + nt * 16 + l15;
        const int p = n >> 6;            // uniform per (wc,nt)
        const int h = n & 63;
        if (p < 2) {                     // q or k: RoPE
            _Float16* __restrict__ outb = (p == 0) ? qh : kh;
            const float invf = __expf(-0.2878231366242557f * (float)(h >> 1));
            #pragma unroll
            for (int r = 0; r < 4; r++) {
                int   row = row0 + wr * 16 + quad * 4 + r;
                float val = acc[nt][r];
                float partner = __shfl_xor(val, 1, 64);
                float ang = (float)(row & (Tn - 1)) * invf;
                float sv, cv;
                __sincosf(ang, &sv, &cv);
                float res = (h & 1) ? fmaf(val, cv,  partner * sv)
                                    : fmaf(val, cv, -partner * sv);
                if (p == 0) res *= 0.125f;
                float resn = __shfl_xor(res, 1, 64);
                if (!(l15 & 1)) {
                    f16x2 pk = { (_Float16)res, (_Float16)resn };
                    *(f16x2*)&outb[(size_t)row * Hn + h] = pk;
                }
            }
        } else {                         // v: store transposed vT[b][h][t]
            int t = (row0 & (Tn - 1)) + wr * 16 + quad * 4;
            f16x4 pv = { (_Float16)acc[nt][0], (_Float16)acc[nt][1],
                         (_Float16)acc[nt][2], (_Float16)acc[nt][3] };
            *(f16x4*)&vT[((size_t)bidx * Hn + h) * Tn + t] = pv;
        }
    }
}

// ---------------------------------------------------------------------------
// attn: barrier-free flash loop, 4-way split-s. QT=16, STL=64, 256 thr =
// 4 waves; wave w processes s-tiles jt = w, w+4, ... with private online-
// softmax state; one barrier + 4-way merge at the end. K and vT B-frags read
// directly from global (L2, XCD-affine via b = blk&7). Row-sum l computed by
// an extra PV MFMA against an all-ones B-frag (no sum shuffle tree).
// qt permuted so each CU's 4 resident blocks have constant total work.
// ---------------------------------------------------------------------------
#define PSP 72

__global__ __launch_bounds__(256) void attn_kernel(
    const _Float16* __restrict__ qh, const _Float16* __restrict__ kh,
    const _Float16* __restrict__ vT, float* __restrict__ out)
{
    __shared__ _Float16 ps[4][16 * PSP];     // wave-private P transpose
    __shared__ float ocomb[4][16][68];
    __shared__ float mlcomb[4][2][16];       // [wave][m|l][row]

    const int blk = blockIdx.x;
    const int b   = blk & 7;                 // batch == XCD affinity
    const int j   = blk >> 3;                // 0..127
    const int jm  = j & 31, g = j >> 5;      // complement permutation
    const int qt  = (g == 0) ? (127 - jm)
                  : (g == 1) ? (64 + jm)
                  : (g == 2) ? (63 - jm) : jm;
    const int t0  = qt * 16;
    const int tid = threadIdx.x;
    const int w = tid >> 6, lane = tid & 63;
    const int quad = lane >> 4, l15 = lane & 15;

    const _Float16* __restrict__ qb = qh + (size_t)b * Tn * Hn;
    const _Float16* __restrict__ kb = kh + (size_t)b * Tn * Hn;
    const _Float16* __restrict__ vb = vT + (size_t)b * Hn * Tn;

    // Q A-frags: registers for the whole loop
    const f16x8 aq0 = *(const f16x8*)&qb[(size_t)(t0 + l15) * Hn +      quad * 8];
    const f16x8 aq1 = *(const f16x8*)&qb[(size_t)(t0 + l15) * Hn + 32 + quad * 8];

    const _Float16 one1 = (_Float16)1.0f;
    const f16x8 onesv = { one1, one1, one1, one1, one1, one1, one1, one1 };

    float m_run[4];
    f32x4 oacc[5] = {};                      // [0..3]=O cols, [4]=row-sum l
    #pragma unroll
    for (int r = 0; r < 4; r++) m_run[r] = -1e30f;

    const int nst = (t0 + 16 + 63) >> 6;     // ceil((t0+16)/64)  [round-5 bug: was t0+80]
    for (int jt = w; jt < nst; jt += 4) {
        const int s0 = jt * 64;

        // K B-frags direct from global
        f16x8 kf[4][2];
        #pragma unroll
        for (int nt = 0; nt < 4; nt++) {
            const _Float16* kp = &kb[(size_t)(s0 + nt * 16 + l15) * Hn + quad * 8];
            kf[nt][0] = *(const f16x8*)kp;
            kf[nt][1] = *(const f16x8*)(kp + 32);
        }
        f32x4 sacc[4];
        #pragma unroll
        for (int nt = 0; nt < 4; nt++) {
            f32x4 z = {};
            z = __builtin_amdgcn_mfma_f32_16x16x32_f16(aq0, kf[nt][0], z, 0, 0, 0);
            z = __builtin_amdgcn_mfma_f32_16x16x32_f16(aq1, kf[nt][1], z, 0, 0, 0);
            sacc[nt] = z;
        }

        // vT B-frags: issue before softmax (independent), consumed by PV
        f16x8 vf[2][4];
        #pragma unroll
        for (int sc = 0; sc < 2; sc++)
            #pragma unroll
            for (int ht = 0; ht < 4; ht++)
                vf[sc][ht] = *(const f16x8*)&vb[(size_t)(ht * 16 + l15) * Tn
                                                + s0 + sc * 32 + quad * 8];

        if (jt == nst - 1) {             // causal mask: only diagonal tile
            #pragma unroll
            for (int nt = 0; nt < 4; nt++)
                #pragma unroll
                for (int r = 0; r < 4; r++) {
                    int scol = s0 + nt * 16 + l15;
                    int trow = t0 + quad * 4 + r;
                    if (scol > trow) sacc[nt][r] = -1e30f;
                }
        }

        // online softmax: max tree only (l comes from the ones-MFMA)
        float pr[4][4];
        #pragma unroll
        for (int r = 0; r < 4; r++) {
            float mx = fmaxf(fmaxf(sacc[0][r], sacc[1][r]),
                             fmaxf(sacc[2][r], sacc[3][r]));
            #pragma unroll
            for (int off = 1; off < 16; off <<= 1)
                mx = fmaxf(mx, __shfl_xor(mx, off, 64));
            float mnew  = fmaxf(m_run[r], mx);
            float alpha = __expf(m_run[r] - mnew);
            m_run[r] = mnew;
            #pragma unroll
            for (int nt = 0; nt < 4; nt++)
                pr[nt][r] = __expf(sacc[nt][r] - mnew);
            #pragma unroll
            for (int ht = 0; ht < 5; ht++)
                oacc[ht][r] = oacc[ht][r] * alpha;
        }

        // P -> ps (wave-private; same-wave RAW, no barrier)
        #pragma unroll
        for (int nt = 0; nt < 4; nt++)
            #pragma unroll
            for (int r = 0; r < 4; r++) {
                float pv = pr[nt][r];
                float pn = __shfl_xor(pv, 1, 64);
                if (!(l15 & 1)) {
                    f16x2 pk = { (_Float16)pv, (_Float16)pn };
                    *(f16x2*)&ps[w][(quad * 4 + r) * PSP + nt * 16 + l15] = pk;
                }
            }

        // O += P V  (8 MFMA) + l += P 1 (2 MFMA)
        #pragma unroll
        for (int sc = 0; sc < 2; sc++) {
            f16x8 ap = *(const f16x8*)&ps[w][l15 * PSP + sc * 32 + quad * 8];
            #pragma unroll
            for (int ht = 0; ht < 4; ht++)
                oacc[ht] = __builtin_amdgcn_mfma_f32_16x16x32_f16(ap, vf[sc][ht],
                                                                  oacc[ht], 0, 0, 0);
            oacc[4] = __builtin_amdgcn_mfma_f32_16x16x32_f16(ap, onesv,
                                                             oacc[4], 0, 0, 0);
        }
    }

    // Write partials, barrier, 4-way merge of online-softmax states.
    #pragma unroll
    for (int r = 0; r < 4; r++) {
        #pragma unroll
        for (int ht = 0; ht < 4; ht++)
            ocomb[w][quad * 4 + r][ht * 16 + l15] = oacc[ht][r];
        if (l15 == 0) {
            mlcomb[w][0][quad * 4 + r] = m_run[r];
            mlcomb[w][1][quad * 4 + r] = oacc[4][r];
        }
    }
    __syncthreads();

    #pragma unroll
    for (int it = 0; it < 4; it++) {
        int idx = tid + it * 256;        // 1024 = 16 rows x 64 h
        int row = idx >> 6, h = idx & 63;
        float m0 = mlcomb[0][0][row], m1 = mlcomb[1][0][row];
        float m2 = mlcomb[2][0][row], m3 = mlcomb[3][0][row];
        float mm = fmaxf(fmaxf(m0, m1), fmaxf(m2, m3));
        float a0 = __expf(m0 - mm), a1 = __expf(m1 - mm);
        float a2 = __expf(m2 - mm), a3 = __expf(m3 - mm);
        float ll = mlcomb[0][1][row] * a0 + mlcomb[1][1][row] * a1
                 + mlcomb[2][1][row] * a2 + mlcomb[3][1][row] * a3;
        float ov = ocomb[0][row][h] * a0 + ocomb[1][row][h] * a1
                 + ocomb[2][row][h] * a2 + ocomb[3][row][h] * a3;
        out[((size_t)b * Tn + t0 + row) * Hn + h] = ov / ll;
    }
}

extern "C" void kernel_launch(void* const* d_in, const int* in_sizes, int n_in,
                              void* d_out, int out_size, void* d_ws, size_t ws_size,
                              hipStream_t stream) {
    const float* x  = (const float*)d_in[0];
    const float* Wq = (const float*)d_in[1];
    const float* Wk = (const float*)d_in[2];
    const float* Wv = (const float*)d_in[3];

    const size_t qkvN = (size_t)BTn * Hn;
    _Float16* qh = (_Float16*)d_ws;
    _Float16* kh = qh + qkvN;
    _Float16* vT = kh + qkvN;                     // [8][64][2048] transposed
    _Float16* Wt = vT + qkvN;                     // [192][1024] f16

    prep_w_kernel<<<48, 256, 0, stream>>>(Wq, Wk, Wv, Wt);
    proj_kernel<<<BTn / 32, 512, 0, stream>>>(x, Wt, qh, kh, vT);
    attn_kernel<<<1024, 256, 0, stream>>>(qh, kh, vT, (float*)d_out);
}